// Round 2
// baseline (177.259 us; speedup 1.0000x reference)
//
#include <hip/hip_runtime.h>

#define BLANK_ID 0
#define EPS 1e-10f

constexpr int B = 8, T = 2048, D = 1024, V = 1024;

// ---------------------------------------------------------------------------
// Phase 1: per-(b,t) softmax stats. One wave64 per row of V=1024 logits.
// Each lane holds 16 elements (4x float4, coalesced: iter j reads floats
// [j*256 + lane*4 .. +3] -> contiguous 1KB per instruction).
// Outputs: pred[row]=argmax, pval[row]=1/sum(exp(l-max)) (== softmax prob of
// the argmax), p0[b]=softmax prob of BLANK at t=0 (fallback path only).
// ---------------------------------------------------------------------------
__global__ __launch_bounds__(256) void k_softmax_stats(
    const float* __restrict__ logits, int* __restrict__ pred,
    float* __restrict__ pval, float* __restrict__ p0) {
  const int wave = threadIdx.x >> 6;
  const int lane = threadIdx.x & 63;
  const int row  = blockIdx.x * 4 + wave;  // [0, B*T)
  const float* rp = logits + (size_t)row * V;

  float4 x[4];
#pragma unroll
  for (int j = 0; j < 4; ++j)
    x[j] = *reinterpret_cast<const float4*>(rp + j * 256 + lane * 4);

  // local max + argmax (first occurrence on ties, matching jnp.argmax)
  float m = x[0].x;
  int idx = lane * 4;
#pragma unroll
  for (int j = 0; j < 4; ++j) {
    const float v[4] = {x[j].x, x[j].y, x[j].z, x[j].w};
#pragma unroll
    for (int k = 0; k < 4; ++k) {
      const int vi = j * 256 + lane * 4 + k;
      if (v[k] > m || (v[k] == m && vi < idx)) { m = v[k]; idx = vi; }
    }
  }
  // wave64 butterfly: (max, min-idx-on-tie) is associative+commutative,
  // all lanes converge to the same result.
#pragma unroll
  for (int off = 32; off > 0; off >>= 1) {
    const float om = __shfl_xor(m, off);
    const int   oi = __shfl_xor(idx, off);
    if (om > m || (om == m && oi < idx)) { m = om; idx = oi; }
  }

  float s = 0.f;
#pragma unroll
  for (int j = 0; j < 4; ++j)
    s += __expf(x[j].x - m) + __expf(x[j].y - m) +
         __expf(x[j].z - m) + __expf(x[j].w - m);
#pragma unroll
  for (int off = 32; off > 0; off >>= 1) s += __shfl_xor(s, off);

  if (lane == 0) {
    pred[row] = idx;
    pval[row] = 1.0f / s;  // exp(max-max)/sum
    if ((row & (T - 1)) == 0) {
      // lane 0's first element is v=0 (BLANK) of this row; row is t=0 of b
      p0[row / T] = __expf(x[0].x - m) / s;
    }
  }
}

// ---------------------------------------------------------------------------
// Phase 2: per-batch segment scan. One block (256 threads x 8 t's) per batch.
// seg_idx is a prefix sum of nonblank-boundaries; since it's monotone in t,
// segment s is exactly the t-range [bpos[s], bpos[s+1]). seg_sum via LDS
// atomics; per-frame weight w[t] = p[t]/(seg_sum+EPS) for contributing frames
// else exactly 0 (phase 3 uses w!=0 to skip loads).
// ---------------------------------------------------------------------------
__global__ __launch_bounds__(256) void k_segment(
    const int* __restrict__ pred, const float* __restrict__ pval,
    const int* __restrict__ lengths, float* __restrict__ w,
    int* __restrict__ bpos, int* __restrict__ nseg,
    float* __restrict__ out_nl) {
  const int b   = blockIdx.x;
  const int tid = threadIdx.x;
  const int len = lengths[b];

  __shared__ float segsum[T];  // 8 KB; n_seg <= T
  __shared__ int   ssum[256];
  for (int i = tid; i < T; i += 256) segsum[i] = 0.f;

  const int t0 = tid * 8;
  bool nbb[8], fis[8];
  float pv[8];
  int c = 0;
#pragma unroll
  for (int j = 0; j < 8; ++j) {
    const int t  = t0 + j;
    const int pt = pred[b * T + t];
    const int pr = (t > 0) ? pred[b * T + t - 1] : -1;
    const bool valid = t < len;
    const bool nb = (pt != BLANK_ID);
    const bool bd = valid && (pt != pr);
    nbb[j] = bd && nb;
    fis[j] = valid && nb;
    pv[j]  = pval[b * T + t];
    c += nbb[j] ? 1 : 0;
  }

  ssum[tid] = c;
  __syncthreads();
  // Hillis-Steele inclusive scan over 256 thread sums
  for (int d2 = 1; d2 < 256; d2 <<= 1) {
    const int v = (tid >= d2) ? ssum[tid - d2] : 0;
    __syncthreads();
    ssum[tid] += v;
    __syncthreads();
  }
  const int excl  = ssum[tid] - c;
  const int total = ssum[255];

  int segj[8];
  int run = excl;
#pragma unroll
  for (int j = 0; j < 8; ++j) {
    if (nbb[j]) {
      bpos[b * (T + 1) + run] = t0 + j;  // unique seg per boundary, no race
      ++run;
    }
    segj[j] = run - 1;  // inclusive cumsum - 1
    if (fis[j] && segj[j] >= 0) atomicAdd(&segsum[segj[j]], pv[j]);
  }
  __syncthreads();
#pragma unroll
  for (int j = 0; j < 8; ++j) {
    float wv = 0.f;
    if (fis[j] && segj[j] >= 0) wv = pv[j] / (segsum[segj[j]] + EPS);
    w[b * T + t0 + j] = wv;
  }

  if (tid == 0) {
    nseg[b] = total;
    bpos[b * (T + 1) + total] = len;  // sentinel end of last segment
    if (out_nl) out_nl[b] = (float)(total > 0 ? total : 1);  // new_lengths
  }
}

// ---------------------------------------------------------------------------
// Phase 3: one block per output row (b,s); 256 threads x float4 = D=1024.
// Rows s >= n_seg write zeros (required: d_out is poisoned). Fallback row
// (n_seg==0) handled inline. Output written once, never re-read ->
// nontemporal stores keep L2 for the hidden_states reads.
// ---------------------------------------------------------------------------
__global__ __launch_bounds__(256) void k_compress(
    const float* __restrict__ hidden, const float* __restrict__ w,
    const int* __restrict__ bpos, const int* __restrict__ nseg,
    const float* __restrict__ p0, const int* __restrict__ lengths,
    float* __restrict__ out) {
  const int s = blockIdx.x;
  const int b = blockIdx.y;
  const int d = threadIdx.x * 4;
  const int n = nseg[b];

  float4 acc = make_float4(0.f, 0.f, 0.f, 0.f);
  if (s < n) {
    const int st = bpos[b * (T + 1) + s];
    const int en = bpos[b * (T + 1) + s + 1];
    for (int t = st; t < en; ++t) {
      const float wt = w[b * T + t];  // uniform across block -> broadcast
      if (wt != 0.f) {                // skip blank/invalid frames entirely
        const float4 h = *reinterpret_cast<const float4*>(
            hidden + ((size_t)(b * T + t)) * D + d);
        acc.x += wt * h.x; acc.y += wt * h.y;
        acc.z += wt * h.z; acc.w += wt * h.w;
      }
    }
  } else if (s == 0 && n == 0) {
    if (lengths[b] >= 1) {
      const float pv = p0[b];
      const float wt = pv / (pv + EPS);
      const float4 h =
          *reinterpret_cast<const float4*>(hidden + (size_t)b * T * D + d);
      acc.x = wt * h.x; acc.y = wt * h.y; acc.z = wt * h.z; acc.w = wt * h.w;
    }
  }
  float* op = out + ((size_t)(b * T + s)) * D + d;
  __builtin_nontemporal_store(acc.x, op + 0);
  __builtin_nontemporal_store(acc.y, op + 1);
  __builtin_nontemporal_store(acc.z, op + 2);
  __builtin_nontemporal_store(acc.w, op + 3);
}

// ---------------------------------------------------------------------------
extern "C" void kernel_launch(void* const* d_in, const int* in_sizes, int n_in,
                              void* d_out, int out_size, void* d_ws,
                              size_t ws_size, hipStream_t stream) {
  const float* hidden  = (const float*)d_in[0];
  const float* logits  = (const float*)d_in[1];
  const int*   lengths = (const int*)d_in[2];
  float* out = (float*)d_out;

  char* ws = (char*)d_ws;
  int*   pred = (int*)ws;   ws += (size_t)B * T * sizeof(int);
  float* pval = (float*)ws; ws += (size_t)B * T * sizeof(float);
  float* wgt  = (float*)ws; ws += (size_t)B * T * sizeof(float);
  int*   bpos = (int*)ws;   ws += (size_t)B * (T + 1) * sizeof(int);
  int*   nseg = (int*)ws;   ws += (size_t)B * sizeof(int);
  float* p0   = (float*)ws; ws += (size_t)B * sizeof(float);

  // tuple output: [compressed (B*T*D floats) | new_lengths (B, as float)]
  float* out_nl =
      (out_size >= B * T * D + B) ? out + (size_t)B * T * D : nullptr;

  k_softmax_stats<<<(B * T) / 4, 256, 0, stream>>>(logits, pred, pval, p0);
  k_segment<<<B, 256, 0, stream>>>(pred, pval, lengths, wgt, bpos, nseg,
                                   out_nl);
  dim3 g3(T, B);
  k_compress<<<g3, 256, 0, stream>>>(hidden, wgt, bpos, nseg, p0, lengths,
                                     out);
}